// Round 3
// baseline (453.325 us; speedup 1.0000x reference)
//
#include <hip/hip_runtime.h>
#include <hip/hip_bf16.h>

// IrrepLinear: out[b, o*25+m] = sum_i x[b, i*25+m] * W[l(m), o, i]  (+bias at m=0)
// GEMM rows=(m,b_local), bf16 MFMA 16x16x32. Block: b-tile 16 x o-tile 64, BK=32,
// 10 waves = 5 m-groups x 2 o-positions, OF=2 o-frags/wave. LDS double-buffered,
// one barrier/step; scatter = 8 same-m scalar loads -> 1 ds_write_b128.

typedef __bf16 bf16x8v __attribute__((ext_vector_type(8)));
typedef float floatx4 __attribute__((ext_vector_type(4)));
typedef unsigned short ushort_t;
typedef unsigned short ushortx4 __attribute__((ext_vector_type(4)));
typedef unsigned short ushortx8 __attribute__((ext_vector_type(8)));

#define ROW_F 12800        // floats per batch row (IN_F*25 = OUT_F*25)
#define BUF_USH 16064      // 32128 B per LDS buffer (400 rows * 80B + swizzle headroom)

__device__ __forceinline__ ushort_t f2bf(float f) {
    __hip_bfloat16 h = __float2bfloat16(f);   // RNE
    return __builtin_bit_cast(ushort_t, h);
}

// Row byte layout: row*80 + 16*tri(m), m=row>>4. Triangle wave keeps the shift
// monotone-safe (|delta| <= 16B between consecutive rows => no overlap at 80B
// stride) while putting m's low bits into the bank index (row*80 alone cannot:
// 16*stride = 0 mod 32 words). Units below: ushorts.
__device__ __forceinline__ int row_ush(int row) {
    int m = row >> 4;
    int t = (m & 8) ? ((15 - m) & 7) : (m & 7);
    return row * 40 + t * 8;
}

// --- weight fp32 [5][512][512] -> bf16 in ws (same layout) ---
__global__ void cvt_w_kernel(const float* __restrict__ w, ushort_t* __restrict__ wb) {
    int i = (blockIdx.x * 256 + threadIdx.x) * 4;   // 1310720 elems, grid 1280x256 exact
    floatx4 v = *reinterpret_cast<const floatx4*>(w + i);
    ushortx4 h;
    h.x = f2bf(v[0]); h.y = f2bf(v[1]); h.z = f2bf(v[2]); h.w = f2bf(v[3]);
    *reinterpret_cast<ushortx4*>(wb + i) = h;
}

__global__ __launch_bounds__(640, 3) void irrep_kernel(
        const float* __restrict__ x, const ushort_t* __restrict__ wb,
        const float* __restrict__ bias, float* __restrict__ out) {
    __shared__ __align__(16) ushort_t Asm[2 * BUF_USH];   // 64256 B

    const int tid = threadIdx.x, lane = tid & 63, wv = tid >> 6;
    const int lr = lane & 15, lh = lane >> 4;

    // XCD swizzle: consecutive 64 blocks on one XCD = 8 b-tiles x all 8 o-siblings
    // -> every x window read once from HBM, 7/8 from L2.
    const int hw = blockIdx.x;
    const int sib = (hw >> 3) & 7;
    const int btile = (hw & 7) | ((hw >> 6) << 3);
    const int b0 = btile * 16, o0 = sib * 64;

    const int g = wv % 5;        // m-group: m = g*5 .. g*5+4
    const int po = wv / 5;       // o-position
    const int ob = o0 + po * 32; // wave covers cols ob + of*16 + lr, of in {0,1}

    // ---- scatter batches: bi in [0,1600) = (bb in 16) x (io in 4) x (m in 25).
    // Each batch: 8 scalar loads x[b][(k0+io*8+j)*25+m] -> 1 ds_write_b128.
    const float* rdp[3]; int wro[3];
#pragma unroll
    for (int ba = 0; ba < 3; ++ba) {
        int bi = tid + ba * 640;
        if (bi < 1600) {
            int bb = bi / 100, r = bi - bb * 100;
            int m = r % 25, io = r / 25;
            rdp[ba] = x + (size_t)(b0 + bb) * ROW_F + io * 8 * 25 + m;
            wro[ba] = row_ush(m * 16 + bb) + io * 8;
        } else { rdp[ba] = x; wro[ba] = 0; }
    }

    float vbuf[3][8];
    auto issue_all = [&]() {
#pragma unroll
        for (int ba = 0; ba < 3; ++ba) if (ba * 640 + tid < 1600) {
#pragma unroll
            for (int j = 0; j < 8; ++j) vbuf[ba][j] = rdp[ba][j * 25];
            rdp[ba] += 800;   // next k-step chunk
        }
    };
    auto scat = [&](int buf) {
#pragma unroll
        for (int ba = 0; ba < 3; ++ba) if (ba * 640 + tid < 1600) {
            ushortx8 w8;
#pragma unroll
            for (int j = 0; j < 8; ++j) w8[j] = f2bf(vbuf[ba][j]);
            *reinterpret_cast<ushortx8*>(&Asm[buf * BUF_USH + wro[ba]]) = w8;
        }
    };

    // ---- B pointers: 3 l-slots (dup-padded) x 2 o-frags
    const ushort_t* wbp[3][2];
    {
        constexpr int LV[5][3] = {{0,1,2},{2,3,3},{3,3,3},{3,4,4},{4,4,4}};
#pragma unroll
        for (int li = 0; li < 3; ++li)
#pragma unroll
            for (int of = 0; of < 2; ++of)
                wbp[li][of] = wb + (size_t)(LV[g][li] * 512 + ob + of * 16 + lr) * 512 + lh * 8;
    }

    // A-frag LDS offsets (constant across steps; cur toggles the base)
    int aoff[5];
#pragma unroll
    for (int mm = 0; mm < 5; ++mm)
        aoff[mm] = row_ush((g * 5 + mm) * 16 + lr) + lh * 8;

    floatx4 acc[5][2];
#pragma unroll
    for (int mm = 0; mm < 5; ++mm)
#pragma unroll
        for (int of = 0; of < 2; ++of) acc[mm][of] = (floatx4){0.f, 0.f, 0.f, 0.f};

    // prologue: stage step 0
    issue_all();
    scat(0);
    __syncthreads();
    int cur = 0;

#pragma unroll 1
    for (int s = 0; s < 16; ++s) {
        if (s < 15) issue_all();              // next step's x, hidden under compute
        bf16x8v bfr[3][2];
#pragma unroll
        for (int li = 0; li < 3; ++li)
#pragma unroll
            for (int of = 0; of < 2; ++of) {
                bfr[li][of] = *reinterpret_cast<const bf16x8v*>(wbp[li][of]);
                wbp[li][of] += 32;            // advance K
            }
        bf16x8v afr[5];
#pragma unroll
        for (int mm = 0; mm < 5; ++mm)
            afr[mm] = *reinterpret_cast<const bf16x8v*>(&Asm[cur * BUF_USH + aoff[mm]]);
        // MFMA: bfr slot index must be compile-time -> predicated per m-group
#pragma unroll
        for (int Gc = 0; Gc < 5; ++Gc) if (g == Gc) {
            constexpr int IDXT[5][5] = {{0,1,1,1,2},{0,0,0,0,1},{0,0,0,0,0},{0,1,1,1,1},{0,0,0,0,0}};
#pragma unroll
            for (int mm = 0; mm < 5; ++mm)
#pragma unroll
                for (int of = 0; of < 2; ++of)
                    acc[mm][of] = __builtin_amdgcn_mfma_f32_16x16x32_bf16(
                        afr[mm], bfr[IDXT[Gc][mm]][of], acc[mm][of], 0, 0, 0);
        }
        if (s < 15) scat(cur ^ 1);            // write next step into other buffer
        __syncthreads();
        cur ^= 1;
    }

    // bias on m=0 only
    if (g == 0) {
        float bv0 = bias[ob + lr], bv1 = bias[ob + 16 + lr];
#pragma unroll
        for (int r = 0; r < 4; ++r) { acc[0][0][r] += bv0; acc[0][1][r] += bv1; }
    }

    // ---- epilogue via LDS: 4 passes of 4 b-rows; stores are contiguous
    // 6400B runs: out + b*12800 + o0*25 + [0,1600)
    float* ep = reinterpret_cast<float*>(Asm);
    constexpr int EPROW = 1608;   // 1600 + pad
#pragma unroll 1
    for (int p = 0; p < 4; ++p) {
        if (lh == p) {
#pragma unroll
            for (int of = 0; of < 2; ++of) {
                int cb = (po * 32 + of * 16 + lr) * 25 + g * 5;
#pragma unroll
                for (int rr = 0; rr < 4; ++rr) {
                    float* dst = ep + rr * EPROW + cb;
                    dst[0] = acc[0][of][rr]; dst[1] = acc[1][of][rr];
                    dst[2] = acc[2][of][rr]; dst[3] = acc[3][of][rr];
                    dst[4] = acc[4][of][rr];
                }
            }
        }
        __syncthreads();
#pragma unroll 1
        for (int idx = tid; idx < 1600; idx += 640) {
            int rr = idx / 400, c4 = idx - rr * 400;
            floatx4 v = *reinterpret_cast<const floatx4*>(ep + rr * EPROW + c4 * 4);
            *reinterpret_cast<floatx4*>(
                out + (size_t)(b0 + p * 4 + rr) * ROW_F + o0 * 25 + c4 * 4) = v;
        }
        __syncthreads();
    }
}

extern "C" void kernel_launch(void* const* d_in, const int* in_sizes, int n_in,
                              void* d_out, int out_size, void* d_ws, size_t ws_size,
                              hipStream_t stream) {
    const float* x    = (const float*)d_in[0];
    const float* w    = (const float*)d_in[1];
    const float* bias = (const float*)d_in[2];
    float* outp       = (float*)d_out;
    ushort_t* wb      = (ushort_t*)d_ws;    // 2.62 MB bf16 weights

    cvt_w_kernel<<<1280, 256, 0, stream>>>(w, wb);
    irrep_kernel<<<2048, 640, 0, stream>>>(x, wb, bias, outp);
}